// Round 8
// baseline (1042.689 us; speedup 1.0000x reference)
//
#include <hip/hip_runtime.h>
#include <hip/hip_bf16.h>
#include <math.h>
#include <cstdint>

static constexpr int NN = 50000;   // nodes
static constexpr int NE = 400000;  // edges
static constexpr int H  = 400;     // hidden dim
static constexpr int NG = 128;     // graphs
static constexpr int NC = 10;      // classes
static constexpr float EPS = 1e-5f;
static constexpr int NB1 = (NN + 255) / 256;   // 196 scan blocks
static constexpr int NKT = 13;                 // K tiles of 32 (400 -> 416)
static constexpr long WMAT = (long)NKT * 400 * 32;   // u16 per blocked weight matrix

typedef unsigned short u16;
typedef __attribute__((ext_vector_type(8))) unsigned short u16x8;
typedef __attribute__((ext_vector_type(4))) unsigned short u16x4;
typedef __attribute__((ext_vector_type(8))) short bf16x8;
typedef __attribute__((ext_vector_type(4))) float f32x4;

__device__ __forceinline__ float bf2f(u16 u) {
    return __uint_as_float(((uint32_t)u) << 16);
}
__device__ __forceinline__ u16 f2bf(float f) {
    uint32_t u = __float_as_uint(f);
    return (u16)((u + 0x7FFFu + ((u >> 16) & 1u)) >> 16);
}
__device__ __forceinline__ void gload_lds16(const void* g, void* lds) {
    __builtin_amdgcn_global_load_lds((const __attribute__((address_space(1))) void*)g,
                                     (__attribute__((address_space(3))) void*)lds, 16, 0, 0);
}

// Activations are stored K-tile-blocked: elem (n, col) lives at
//   ((col>>5) * NN + n) * 32 + (col & 31)
// so a 128-row x 32-col GEMM tile is 8 KB CONTIGUOUS. Weights likewise:
//   ((col>>5) * 400 + c) * 32 + (col & 31), zero-padded cols 400..415.

// ---------------- CSR build ----------------

__global__ void k_count(const int* __restrict__ dst, int* __restrict__ deg) {
    int e = blockIdx.x * blockDim.x + threadIdx.x;
    if (e < NE) atomicAdd(&deg[dst[e]], 1);
}

__global__ __launch_bounds__(256) void k_scan1(const int* __restrict__ deg,
                                               int* __restrict__ part,
                                               int* __restrict__ btot) {
    __shared__ int sd[256];
    int t = threadIdx.x;
    int i = blockIdx.x * 256 + t;
    int v = (i < NN) ? deg[i] : 0;
    sd[t] = v;
    __syncthreads();
#pragma unroll
    for (int off = 1; off < 256; off <<= 1) {
        int x = (t >= off) ? sd[t - off] : 0;
        __syncthreads();
        sd[t] += x;
        __syncthreads();
    }
    if (i < NN) part[i] = sd[t];
    if (t == 255) btot[blockIdx.x] = sd[255];
}

__global__ __launch_bounds__(256) void k_scan2(int* __restrict__ btot) {
    __shared__ int sd[256];
    int t = threadIdx.x;
    int v = (t < NB1) ? btot[t] : 0;
    sd[t] = v;
    __syncthreads();
#pragma unroll
    for (int off = 1; off < 256; off <<= 1) {
        int x = (t >= off) ? sd[t - off] : 0;
        __syncthreads();
        sd[t] += x;
        __syncthreads();
    }
    if (t < NB1) btot[t] = sd[t];
}

__global__ __launch_bounds__(256) void k_scan3(const int* __restrict__ part,
                                               const int* __restrict__ btot,
                                               const int* __restrict__ deg,
                                               int* __restrict__ rowp,
                                               int* __restrict__ cur) {
    int i = blockIdx.x * 256 + threadIdx.x;
    if (i < NN) {
        int s = part[i] + (blockIdx.x ? btot[blockIdx.x - 1] : 0);
        rowp[i + 1] = s;
        cur[i] = s - deg[i];
    }
    if (i == 0) rowp[0] = 0;
}

__global__ void k_scatter(const int* __restrict__ src, const int* __restrict__ dst,
                          int* __restrict__ cur, int* __restrict__ csrc) {
    int e = blockIdx.x * blockDim.x + threadIdx.x;
    if (e < NE) {
        int d = dst[e];
        int p = atomicAdd(&cur[d], 1);
        csrc[p] = src[e];
    }
}

// ---------------- weights fp32 -> bf16 blocked [mat][kt][400][32] ----------------

__global__ void k_cvtw_all(const float* __restrict__ s0, const float* __restrict__ s1,
                           const float* __restrict__ s2, const float* __restrict__ s3,
                           const float* __restrict__ s4, u16* __restrict__ dst) {
    int i = blockIdx.x * blockDim.x + threadIdx.x;   // over 8*13*400*4
    if (i >= 8 * NKT * 400 * 4) return;
    int mat = i / (NKT * 400 * 4);
    int rem = i - mat * (NKT * 400 * 4);
    int kt  = rem / (400 * 4);
    int rem2 = rem - kt * (400 * 4);
    int row = rem2 >> 2, q = rem2 & 3;
    int col = kt * 32 + q * 8;
    u16x8 o = {0, 0, 0, 0, 0, 0, 0, 0};
    if (col < 400) {
        const float* s;
        if (mat == 0)      s = s0 + (long)row * 400;
        else if (mat == 1) s = s1 + (long)row * 400;
        else if (mat < 4)  s = s2 + (long)(mat - 2) * 400 * 400 + (long)row * 400;
        else if (mat < 6)  s = s3 + (long)(mat - 4) * 400 * 400 + (long)row * 400;
        else               s = s4 + (long)(mat - 6) * 400 * 400 + (long)row * 400;
        float4 a = *(const float4*)(s + col);
        float4 b = *(const float4*)(s + col + 4);
        o[0] = f2bf(a.x); o[1] = f2bf(a.y); o[2] = f2bf(a.z); o[3] = f2bf(a.w);
        o[4] = f2bf(b.x); o[5] = f2bf(b.y); o[6] = f2bf(b.z); o[7] = f2bf(b.w);
    }
    *(u16x8*)(dst + (long)mat * WMAT + ((long)kt * 400 + row) * 32 + q * 8) = o;
}

// ---------------- aggregation ----------------

__global__ void k_agg0(const float* __restrict__ x, const int* __restrict__ rowp,
                       const int* __restrict__ csrc, float* __restrict__ out) {
    int n = blockIdx.x * blockDim.x + threadIdx.x;
    if (n >= NN) return;
    float4 acc = make_float4(0.f, 0.f, 0.f, 0.f);
    int b = rowp[n], e = rowp[n + 1];
    for (int p = b; p < e; ++p) {
        float4 v = ((const float4*)x)[csrc[p]];
        acc.x += v.x; acc.y += v.y; acc.z += v.z; acc.w += v.w;
    }
    ((float4*)out)[n] = acc;
}

// one wave per node; lanes 0..49 each own 8 features (blocked layout)
__global__ __launch_bounds__(256) void k_aggH(const u16* __restrict__ h,
                                              const int* __restrict__ rowp,
                                              const int* __restrict__ csrc,
                                              u16* __restrict__ out) {
    int n = (blockIdx.x << 2) + (threadIdx.x >> 6);
    if (n >= NN) return;
    int l = threadIdx.x & 63;
    if (l >= 50) return;
    long boff = ((long)(l >> 2) * NN) * 32 + (l & 3) * 8;
    int b = rowp[n], e = rowp[n + 1];
    float acc[8] = {0.f, 0.f, 0.f, 0.f, 0.f, 0.f, 0.f, 0.f};
    for (int p = b; p < e; ++p) {
        u16x8 v = *(const u16x8*)(h + boff + (long)csrc[p] * 32);
#pragma unroll
        for (int q = 0; q < 8; ++q) acc[q] += bf2f(v[q]);
    }
    u16x8 o;
#pragma unroll
    for (int q = 0; q < 8; ++q) o[q] = f2bf(acc[q]);
    *(u16x8*)(out + boff + (long)n * 32) = o;
}

// ---------------- first linear (K = 4), blocked bf16 out ----------------

__global__ void k_lin0(const float* __restrict__ a4, const float* __restrict__ w,
                       const float* __restrict__ b, u16* __restrict__ out) {
    long i = (long)blockIdx.x * blockDim.x + threadIdx.x;   // over NN*100
    if (i >= (long)NN * 100) return;
    int n = (int)(i / 100), q = (int)(i - (long)n * 100);
    int j0 = q * 4;
    float4 av = ((const float4*)a4)[n];
    u16x4 o;
#pragma unroll
    for (int jj = 0; jj < 4; ++jj) {
        float4 wv = ((const float4*)w)[j0 + jj];
        float s = fmaf(av.x, wv.x, fmaf(av.y, wv.y, fmaf(av.z, wv.z, av.w * wv.w)));
        o[jj] = f2bf(s + b[j0 + jj]);
    }
    *(u16x4*)(out + ((long)(j0 >> 5) * NN + n) * 32 + (j0 & 31)) = o;
}

// ---------------- BN stats over blocked bf16 buffer (after lin0 only) ----------------

__global__ __launch_bounds__(256) void k_statsv(const u16* __restrict__ z,
                                                float* __restrict__ stats) {
    __shared__ float ls[800];
    int t = threadIdx.x;
    for (int i = t; i < 800; i += 256) ls[i] = 0.f;
    __syncthreads();
    if (t < 250) {
        int sub = t / 50, seg = t % 50;
        long boff = ((long)(seg >> 2) * NN) * 32 + (seg & 3) * 8;
        float s[8] = {0, 0, 0, 0, 0, 0, 0, 0};
        float q[8] = {0, 0, 0, 0, 0, 0, 0, 0};
        for (int r = blockIdx.x * 5 + sub; r < NN; r += gridDim.x * 5) {
            u16x8 v = *(const u16x8*)(z + boff + (long)r * 32);
#pragma unroll
            for (int j = 0; j < 8; ++j) {
                float f = bf2f(v[j]);
                s[j] += f; q[j] += f * f;
            }
        }
#pragma unroll
        for (int j = 0; j < 8; ++j) {
            atomicAdd(&ls[seg * 8 + j], s[j]);
            atomicAdd(&ls[400 + seg * 8 + j], q[j]);
        }
    }
    __syncthreads();
    for (int i = t; i < 800; i += 256) atomicAdd(&stats[i], ls[i]);
}

__global__ void k_finalize(float* __restrict__ stats, const float* __restrict__ g,
                           const float* __restrict__ be, float* __restrict__ scale,
                           float* __restrict__ shift) {
    int j = blockIdx.x * blockDim.x + threadIdx.x;
    if (j >= H) return;
    float m = stats[j] / NN;
    float v = stats[H + j] / NN - m * m;
    v = fmaxf(v, 0.f);
    float rs = rsqrtf(v + EPS);
    float sc = g[j] * rs;
    scale[j] = sc;
    shift[j] = be[j] - m * sc;
    stats[j] = 0.f;          // self-clean for next use
    stats[H + j] = 0.f;
}

// ---------------- BN+ReLU elementwise, in place (blocked) ----------------

__global__ __launch_bounds__(256) void k_bnrelu(u16* __restrict__ z,
                                                const float* __restrict__ scale,
                                                const float* __restrict__ shift) {
    long i = (long)blockIdx.x * 256 + threadIdx.x;   // over 13*NN*4 u16x8 slots
    if (i >= (long)NKT * NN * 4) return;
    int col = (int)(i / (NN * 4)) * 32 + (int)(i & 3) * 8;
    if (col >= 400) return;                          // kt12 pad chunks
    u16* p = z + i * 8;
    u16x8 v = *(const u16x8*)p;
    float4 s0 = *(const float4*)(scale + col);
    float4 s1 = *(const float4*)(scale + col + 4);
    float4 h0 = *(const float4*)(shift + col);
    float4 h1 = *(const float4*)(shift + col + 4);
    u16x8 o;
    o[0] = f2bf(fmaxf(fmaf(bf2f(v[0]), s0.x, h0.x), 0.f));
    o[1] = f2bf(fmaxf(fmaf(bf2f(v[1]), s0.y, h0.y), 0.f));
    o[2] = f2bf(fmaxf(fmaf(bf2f(v[2]), s0.z, h0.z), 0.f));
    o[3] = f2bf(fmaxf(fmaf(bf2f(v[3]), s0.w, h0.w), 0.f));
    o[4] = f2bf(fmaxf(fmaf(bf2f(v[4]), s1.x, h1.x), 0.f));
    o[5] = f2bf(fmaxf(fmaf(bf2f(v[5]), s1.y, h1.y), 0.f));
    o[6] = f2bf(fmaxf(fmaf(bf2f(v[6]), s1.z, h1.z), 0.f));
    o[7] = f2bf(fmaxf(fmaf(bf2f(v[7]), s1.w, h1.w), 0.f));
    *(u16x8*)p = o;
}

// ---------------- MFMA GEMM: blocked streaming loads, counted-vmcnt pipeline ----------------
// out[n][c] = sum_j A[n][j] * W[c][j] + bias[c]; blocked A (M x 13kt x 32),
// blocked W (13kt x 400 x 32, zero-pad kt12). Tile 128x80, 3 LDS buffers,
// vmcnt(3) depth-2 pipeline, raw s_barrier, XOR slot swizzle (conflict-free, R7).
// A-tile = 8 KB contiguous, B-tile = 5 KB contiguous -> pure streaming fetch.

template <bool STATS, bool POOL>
__global__ __launch_bounds__(256) void gemm_mfma(const u16* __restrict__ A,
                                                 const u16* __restrict__ Wb,
                                                 const float* __restrict__ bias,
                                                 u16* __restrict__ out,
                                                 float* __restrict__ stats,
                                                 const int* __restrict__ batch,
                                                 float* __restrict__ pools,
                                                 int poolOff, int M) {
    constexpr int BUF = 6656;            // u16: A 4096 + B 2560
    __shared__ u16 lds[3 * BUF];         // 39,936 B -> 4 blocks/CU

    const int t = threadIdx.x;
    // bijective XCD swizzle (nwg = 1955, not divisible by 8)
    const int nwg = gridDim.x;
    const int q8 = nwg >> 3, r8 = nwg & 7;
    const int xcd = blockIdx.x & 7, jj = blockIdx.x >> 3;
    const int wgid = (xcd < r8 ? xcd * (q8 + 1) : r8 * (q8 + 1) + (xcd - r8) * q8) + jj;
    const int bm = (wgid / 5) * 128;
    const int bn = (wgid % 5) * 80;
    const int w = t >> 6, l = t & 63;

    // lane source offset inside a 1KB (512-u16) seg, inverse-XOR pre-swizzled:
    // lane l fills LDS granule l (row l>>2, slot l&3); it must fetch chunk
    // (l&3) ^ ((l>>3)&3) of its row.
    const int laneoff = (l >> 2) * 32 + (((l & 3) ^ ((l >> 3) & 3)) << 3);

    auto stageTile = [&](int b, int kt) {
        u16* dst = lds + b * BUF;
        const u16* Ab = A + ((long)kt * NN + bm) * 32 + laneoff;
        const u16* Bb = Wb + ((long)kt * 400 + bn) * 32 + laneoff;
        gload_lds16(Ab + w * 512, dst + w * 512);              // A seg w
        gload_lds16(Ab + (w + 4) * 512, dst + (w + 4) * 512);  // A seg w+4
        gload_lds16(Bb + w * 512, dst + 4096 + w * 512);       // B seg w
        if (w == 0)
            gload_lds16(Bb + 4 * 512, dst + 4096 + 4 * 512);   // B seg 4
    };

    f32x4 acc[2][5];
#pragma unroll
    for (int i = 0; i < 2; ++i)
#pragma unroll
        for (int c = 0; c < 5; ++c)
            acc[i][c] = (f32x4){0.f, 0.f, 0.f, 0.f};

    const int r16 = l & 15;
    const int cc  = l >> 4;                          // logical k-chunk 0..3
    const int swz = r16 * 32 + (((cc ^ ((r16 >> 1) & 3))) << 3);

    auto computeTile = [&](int b) {
        const u16* base = lds + b * BUF;
        const u16* ab = base + w * 1024 + swz;       // segs 2w, 2w+1
        const u16* bb = base + 4096 + swz;
        bf16x8 fa0 = *(const bf16x8*)ab;
        bf16x8 fa1 = *(const bf16x8*)(ab + 512);
        __builtin_amdgcn_s_setprio(1);
#pragma unroll
        for (int c = 0; c < 5; ++c) {
            bf16x8 fb = *(const bf16x8*)(bb + c * 512);
            acc[0][c] = __builtin_amdgcn_mfma_f32_16x16x32_bf16(fa0, fb, acc[0][c], 0, 0, 0);
            acc[1][c] = __builtin_amdgcn_mfma_f32_16x16x32_bf16(fa1, fb, acc[1][c], 0, 0, 0);
        }
        __builtin_amdgcn_s_setprio(0);
    };

    // prologue: tiles 0,1 in flight
    stageTile(0, 0);
    stageTile(1, 1);

    int bc = 0, bs = 2;
#pragma unroll 1
    for (int s = 0; s < NKT - 1; ++s) {
        asm volatile("s_waitcnt vmcnt(3)" ::: "memory");   // own tile-s loads done
        __builtin_amdgcn_s_barrier();                      // all waves' tile-s done
        if (s + 2 < NKT) stageTile(bs, s + 2);
        computeTile(bc);
        if (++bc == 3) bc = 0;
        if (++bs == 3) bs = 0;
    }
    asm volatile("s_waitcnt vmcnt(0)" ::: "memory");
    __builtin_amdgcn_s_barrier();
    computeTile(bc);

    // ---- epilogue (tile LDS now dead; alias stats/pool arrays onto it) ----
    float* sst  = (float*)lds;           // 160 floats
    float* pacc = (float*)lds + 160;     // 480 floats
    __syncthreads();
    if (STATS) for (int i = t; i < 160; i += 256) sst[i] = 0.f;
    if (POOL)  for (int i = t; i < 480; i += 256) pacc[i] = 0.f;
    __syncthreads();

    int sg0 = 0, span = 0;
    int grow[2][4];
    if (POOL) {
        sg0 = batch[min(bm, M - 1)];
        span = batch[min(bm + 127, M - 1)] - sg0 + 1;
#pragma unroll
        for (int i = 0; i < 2; ++i) {
            int rbase = bm + w * 32 + i * 16 + (l >> 4) * 4;
#pragma unroll
            for (int r = 0; r < 4; ++r)
                grow[i][r] = (rbase + r < M) ? batch[rbase + r] : -1;
        }
    }

    // C/D layout: col=lane&15, row=(lane>>4)*4+reg. Blocked store.
    float ssum[5], sqq[5];
#pragma unroll
    for (int c = 0; c < 5; ++c) { ssum[c] = 0.f; sqq[c] = 0.f; }
#pragma unroll
    for (int i = 0; i < 2; ++i) {
        const int rbase = bm + w * 32 + i * 16 + (l >> 4) * 4;
#pragma unroll
        for (int c = 0; c < 5; ++c) {
            const int cbase = bn + c * 16;
            const int col = cbase + (l & 15);
            const float bv = bias[col];
            u16* obase = out + ((long)(cbase >> 5) * NN) * 32 + (cbase & 31) + (l & 15);
#pragma unroll
            for (int r = 0; r < 4; ++r) {
                const int row = rbase + r;
                if (row < M) {
                    float z = acc[i][c][r] + bv;
                    obase[(long)row * 32] = f2bf(z);
                    if (STATS) { ssum[c] += z; sqq[c] += z * z; }
                    if (POOL) {
                        int g = grow[i][r];
                        if (span <= 6)
                            atomicAdd(&pacc[(g - sg0) * 80 + c * 16 + (l & 15)], z);
                        else
                            atomicAdd(&pools[(long)g * 1200 + poolOff + col], z);
                    }
                }
            }
        }
    }
    if (STATS) {
#pragma unroll
        for (int c = 0; c < 5; ++c) {
            ssum[c] += __shfl_xor(ssum[c], 16); ssum[c] += __shfl_xor(ssum[c], 32);
            sqq[c]  += __shfl_xor(sqq[c], 16);  sqq[c]  += __shfl_xor(sqq[c], 32);
        }
        if (l < 16) {
#pragma unroll
            for (int c = 0; c < 5; ++c) {
                atomicAdd(&sst[c * 16 + l], ssum[c]);
                atomicAdd(&sst[80 + c * 16 + l], sqq[c]);
            }
        }
        __syncthreads();
        if (t < 80)       atomicAdd(&stats[bn + t], sst[t]);
        else if (t < 160) atomicAdd(&stats[H + bn + (t - 80)], sst[t]);
    }
    if (POOL) {
        __syncthreads();
        if (span <= 6) {
            int nsp = span * 80;
            for (int i = t; i < nsp; i += 256) {
                atomicAdd(&pools[(long)(sg0 + i / 80) * 1200 + poolOff + bn + (i % 80)],
                          pacc[i]);
            }
        }
    }
}

// ---------------- readout ----------------

__global__ __launch_bounds__(256) void k_lin1(const float* __restrict__ pools,
                                              const float* __restrict__ w1,
                                              const float* __restrict__ b1,
                                              float* __restrict__ zz) {
    __shared__ __align__(16) float xg[1200];
    int band = blockIdx.x, g = blockIdx.y, t = threadIdx.x;
    for (int i = t; i < 1200; i += 256) xg[i] = pools[(long)g * 1200 + i];
    __syncthreads();
    if (t < 240) {
        int j = band * 120 + (t >> 1);
        int kh = t & 1;
        const float4* wr = (const float4*)(w1 + (long)j * 1200 + kh * 600);
        const float4* xr = (const float4*)(xg + kh * 600);
        float s = 0.f;
        for (int q = 0; q < 150; ++q) {
            float4 a = xr[q], b = wr[q];
            s = fmaf(a.x, b.x, s); s = fmaf(a.y, b.y, s);
            s = fmaf(a.z, b.z, s); s = fmaf(a.w, b.w, s);
        }
        s += __shfl_xor(s, 1);
        if (!kh) zz[(long)g * 600 + j] = fmaxf(s + b1[j], 0.f);
    }
}

__global__ __launch_bounds__(64) void k_lin2(const float* __restrict__ zz,
                                             const float* __restrict__ w2,
                                             const float* __restrict__ b2,
                                             float* __restrict__ out) {
    int g = blockIdx.x;
    int l = threadIdx.x;
    float p[NC];
#pragma unroll
    for (int c = 0; c < NC; ++c) p[c] = 0.f;
    for (int k = l; k < 600; k += 64) {
        float zv = zz[(long)g * 600 + k];
#pragma unroll
        for (int c = 0; c < NC; ++c) p[c] = fmaf(zv, w2[c * 600 + k], p[c]);
    }
#pragma unroll
    for (int c = 0; c < NC; ++c)
#pragma unroll
        for (int o = 32; o; o >>= 1) p[c] += __shfl_xor(p[c], o);
    if (l == 0) {
        float lg[NC];
        float mx = -1e30f;
#pragma unroll
        for (int c = 0; c < NC; ++c) { lg[c] = p[c] + b2[c]; mx = fmaxf(mx, lg[c]); }
        float se = 0.f;
#pragma unroll
        for (int c = 0; c < NC; ++c) se += expf(lg[c] - mx);
        float lse = logf(se);
#pragma unroll
        for (int c = 0; c < NC; ++c) out[(long)g * NC + c] = lg[c] - mx - lse;
    }
}

// ---------------- launch ----------------

extern "C" void kernel_launch(void* const* d_in, const int* in_sizes, int n_in,
                              void* d_out, int out_size, void* d_ws, size_t ws_size,
                              hipStream_t stream) {
    const float* x      = (const float*)d_in[0];
    const int*   ei     = (const int*)d_in[1];
    const int*   batch  = (const int*)d_in[2];
    const float* c0_w1  = (const float*)d_in[4];
    const float* c0_b1  = (const float*)d_in[5];
    const float* c0_g1  = (const float*)d_in[6];
    const float* c0_be1 = (const float*)d_in[7];
    const float* c0_w2  = (const float*)d_in[8];
    const float* c0_b2  = (const float*)d_in[9];
    const float* c0_g2  = (const float*)d_in[10];
    const float* c0_be2 = (const float*)d_in[11];
    const float* c0_w3  = (const float*)d_in[12];
    const float* c0_b3  = (const float*)d_in[13];
    const float* cw1    = (const float*)d_in[14];
    const float* cb1    = (const float*)d_in[15];
    const float* cg1    = (const float*)d_in[16];
    const float* cbe1   = (const float*)d_in[17];
    const float* cw2    = (const float*)d_in[18];
    const float* cb2    = (const float*)d_in[19];
    const float* cg2    = (const float*)d_in[20];
    const float* cbe2   = (const float*)d_in[21];
    const float* cw3    = (const float*)d_in[22];
    const float* cb3    = (const float*)d_in[23];
    const float* lin1_w = (const float*)d_in[24];
    const float* lin1_b = (const float*)d_in[25];
    const float* lin2_w = (const float*)d_in[26];
    const float* lin2_b = (const float*)d_in[27];

    const int* src = ei;
    const int* dst = ei + NE;

    char* ws = (char*)d_ws;
    size_t off = 0;
    auto alloc = [&](size_t bytes) {
        void* p = ws + off;
        off += (bytes + 255) & ~(size_t)255;
        return p;
    };
    const size_t actSz = ((size_t)NKT * NN * 32 + 8192) * 2;   // blocked + panel overread pad
    u16*   bufh  = (u16*)alloc(actSz);
    u16*   bufa  = (u16*)alloc(actSz);
    float* agg0  = (float*)alloc((size_t)NN * 4 * 4);
    float* stats = (float*)alloc(2 * H * 4);
    float* scale = (float*)alloc(H * 4);
    float* shift = (float*)alloc(H * 4);
    float* pools = (float*)alloc((size_t)NG * 3 * H * 4);
    float* zz    = (float*)alloc((size_t)NG * 600 * 4);
    u16*   wpad  = (u16*)alloc((size_t)8 * WMAT * 2);   // blocked bf16 weights
    int*   deg   = (int*)alloc((size_t)NN * 4);
    int*   rowp  = (int*)alloc((size_t)(NN + 1) * 4);
    int*   cur   = (int*)alloc((size_t)NN * 4);
    int*   csrc  = (int*)alloc((size_t)NE * 4);
    int*   part  = (int*)alloc((size_t)NN * 4);
    int*   btot  = (int*)alloc((size_t)NB1 * 4);

    auto wp = [&](int mat) { return wpad + (size_t)mat * WMAT; };

    hipMemsetAsync(deg, 0, (size_t)NN * 4, stream);
    hipMemsetAsync(stats, 0, 2 * H * 4, stream);
    hipMemsetAsync(pools, 0, (size_t)NG * 3 * H * 4, stream);

    k_cvtw_all<<<(8 * NKT * 400 * 4 + 255) / 256, 256, 0, stream>>>(c0_w2, c0_w3, cw1, cw2,
                                                                    cw3, wpad);

    // CSR build
    k_count<<<(NE + 255) / 256, 256, 0, stream>>>(dst, deg);
    k_scan1<<<NB1, 256, 0, stream>>>(deg, part, btot);
    k_scan2<<<1, 256, 0, stream>>>(btot);
    k_scan3<<<NB1, 256, 0, stream>>>(part, btot, deg, rowp, cur);
    k_scatter<<<(NE + 255) / 256, 256, 0, stream>>>(src, dst, cur, csrc);

    const int ngemm = ((NN + 127) / 128) * 5;   // 1955 blocks
    const int nbn   = (int)(((long)NKT * NN * 4 + 255) / 256);

    // layer 0
    k_agg0<<<(NN + 255) / 256, 256, 0, stream>>>(x, rowp, csrc, agg0);
    k_lin0<<<(int)(((long)NN * 100 + 255) / 256), 256, 0, stream>>>(agg0, c0_w1, c0_b1, bufh);
    k_statsv<<<96, 256, 0, stream>>>(bufh, stats);
    k_finalize<<<2, 256, 0, stream>>>(stats, c0_g1, c0_be1, scale, shift);
    k_bnrelu<<<nbn, 256, 0, stream>>>(bufh, scale, shift);
    gemm_mfma<true, false><<<ngemm, 256, 0, stream>>>(bufh, wp(0), c0_b2, bufa, stats,
                                                      nullptr, nullptr, 0, NN);
    k_finalize<<<2, 256, 0, stream>>>(stats, c0_g2, c0_be2, scale, shift);
    k_bnrelu<<<nbn, 256, 0, stream>>>(bufa, scale, shift);
    gemm_mfma<false, true><<<ngemm, 256, 0, stream>>>(bufa, wp(1), c0_b3, bufh, nullptr,
                                                      batch, pools, 0, NN);

    // layers 1..2
    for (int l = 0; l < 2; ++l) {
        k_aggH<<<(NN + 3) / 4, 256, 0, stream>>>(bufh, rowp, csrc, bufa);
        gemm_mfma<true, false><<<ngemm, 256, 0, stream>>>(bufa, wp(2 + l), cb1 + l * H,
                                                          bufh, stats, nullptr, nullptr,
                                                          0, NN);
        k_finalize<<<2, 256, 0, stream>>>(stats, cg1 + l * H, cbe1 + l * H, scale, shift);
        k_bnrelu<<<nbn, 256, 0, stream>>>(bufh, scale, shift);
        gemm_mfma<true, false><<<ngemm, 256, 0, stream>>>(bufh, wp(4 + l), cb2 + l * H,
                                                          bufa, stats, nullptr, nullptr,
                                                          0, NN);
        k_finalize<<<2, 256, 0, stream>>>(stats, cg2 + l * H, cbe2 + l * H, scale, shift);
        k_bnrelu<<<nbn, 256, 0, stream>>>(bufa, scale, shift);
        gemm_mfma<false, true><<<ngemm, 256, 0, stream>>>(bufa, wp(6 + l), cb3 + l * H,
                                                          bufh, nullptr, batch, pools,
                                                          (l + 1) * H, NN);
    }

    // readout
    dim3 gl1(5, NG);
    k_lin1<<<gl1, 256, 0, stream>>>(pools, lin1_w, lin1_b, zz);
    k_lin2<<<NG, 64, 0, stream>>>(zz, lin2_w, lin2_b, (float*)d_out);
}

// Round 9
// 992.316 us; speedup vs baseline: 1.0508x; 1.0508x over previous
//
#include <hip/hip_runtime.h>
#include <hip/hip_bf16.h>
#include <math.h>
#include <cstdint>

static constexpr int NN = 50000;   // nodes
static constexpr int NE = 400000;  // edges
static constexpr int H  = 400;     // hidden dim
static constexpr int NG = 128;     // graphs
static constexpr int NC = 10;      // classes
static constexpr float EPS = 1e-5f;
static constexpr int NB1 = (NN + 255) / 256;   // 196 scan blocks
static constexpr int KP  = 416;                // padded K for weights

typedef unsigned short u16;
typedef __attribute__((ext_vector_type(8))) unsigned short u16x8;
typedef __attribute__((ext_vector_type(4))) unsigned short u16x4;
typedef __attribute__((ext_vector_type(8))) short bf16x8;
typedef __attribute__((ext_vector_type(4))) float f32x4;

__device__ __forceinline__ float bf2f(u16 u) {
    return __uint_as_float(((uint32_t)u) << 16);
}
__device__ __forceinline__ u16 f2bf(float f) {
    uint32_t u = __float_as_uint(f);
    return (u16)((u + 0x7FFFu + ((u >> 16) & 1u)) >> 16);
}
__device__ __forceinline__ void gload_lds16(const void* g, void* lds) {
    __builtin_amdgcn_global_load_lds((const __attribute__((address_space(1))) void*)g,
                                     (__attribute__((address_space(3))) void*)lds, 16, 0, 0);
}

// ---------------- CSR build ----------------

__global__ void k_count(const int* __restrict__ dst, int* __restrict__ deg) {
    int e = blockIdx.x * blockDim.x + threadIdx.x;
    if (e < NE) atomicAdd(&deg[dst[e]], 1);
}

__global__ __launch_bounds__(256) void k_scan1(const int* __restrict__ deg,
                                               int* __restrict__ part,
                                               int* __restrict__ btot) {
    __shared__ int sd[256];
    int t = threadIdx.x;
    int i = blockIdx.x * 256 + t;
    int v = (i < NN) ? deg[i] : 0;
    sd[t] = v;
    __syncthreads();
#pragma unroll
    for (int off = 1; off < 256; off <<= 1) {
        int x = (t >= off) ? sd[t - off] : 0;
        __syncthreads();
        sd[t] += x;
        __syncthreads();
    }
    if (i < NN) part[i] = sd[t];
    if (t == 255) btot[blockIdx.x] = sd[255];
}

__global__ __launch_bounds__(256) void k_scan2(int* __restrict__ btot) {
    __shared__ int sd[256];
    int t = threadIdx.x;
    int v = (t < NB1) ? btot[t] : 0;
    sd[t] = v;
    __syncthreads();
#pragma unroll
    for (int off = 1; off < 256; off <<= 1) {
        int x = (t >= off) ? sd[t - off] : 0;
        __syncthreads();
        sd[t] += x;
        __syncthreads();
    }
    if (t < NB1) btot[t] = sd[t];
}

__global__ __launch_bounds__(256) void k_scan3(const int* __restrict__ part,
                                               const int* __restrict__ btot,
                                               const int* __restrict__ deg,
                                               int* __restrict__ rowp,
                                               int* __restrict__ cur) {
    int i = blockIdx.x * 256 + threadIdx.x;
    if (i < NN) {
        int s = part[i] + (blockIdx.x ? btot[blockIdx.x - 1] : 0);
        rowp[i + 1] = s;
        cur[i] = s - deg[i];
    }
    if (i == 0) rowp[0] = 0;
}

__global__ void k_scatter(const int* __restrict__ src, const int* __restrict__ dst,
                          int* __restrict__ cur, int* __restrict__ csrc) {
    int e = blockIdx.x * blockDim.x + threadIdx.x;
    if (e < NE) {
        int d = dst[e];
        int p = atomicAdd(&cur[d], 1);
        csrc[p] = src[e];
    }
}

// ---------------- weights fp32 -> bf16, padded to [8*400][416] (zeros k>=400) ----------------

__global__ void k_cvtw_all(const float* __restrict__ s0, const float* __restrict__ s1,
                           const float* __restrict__ s2, const float* __restrict__ s3,
                           const float* __restrict__ s4, u16* __restrict__ dst) {
    int i = blockIdx.x * blockDim.x + threadIdx.x;   // over 8*400*52
    if (i >= 8 * 400 * 52) return;
    int rc = i / 52;              // 0..3199 global row
    int c8 = (i % 52) * 8;
    u16x8 o = {0, 0, 0, 0, 0, 0, 0, 0};
    if (c8 < 400) {
        int mat = rc / 400, row = rc % 400;
        const float* s;
        if (mat == 0)      s = s0 + (long)row * 400;
        else if (mat == 1) s = s1 + (long)row * 400;
        else if (mat < 4)  s = s2 + (long)(mat - 2) * 400 * 400 + (long)row * 400;
        else if (mat < 6)  s = s3 + (long)(mat - 4) * 400 * 400 + (long)row * 400;
        else               s = s4 + (long)(mat - 6) * 400 * 400 + (long)row * 400;
        float4 a = *(const float4*)(s + c8);
        float4 b = *(const float4*)(s + c8 + 4);
        o[0] = f2bf(a.x); o[1] = f2bf(a.y); o[2] = f2bf(a.z); o[3] = f2bf(a.w);
        o[4] = f2bf(b.x); o[5] = f2bf(b.y); o[6] = f2bf(b.z); o[7] = f2bf(b.w);
    }
    *(u16x8*)(dst + (long)rc * KP + c8) = o;
}

// ---------------- aggregation ----------------

__global__ void k_agg0(const float* __restrict__ x, const int* __restrict__ rowp,
                       const int* __restrict__ csrc, float* __restrict__ out) {
    int n = blockIdx.x * blockDim.x + threadIdx.x;
    if (n >= NN) return;
    float4 acc = make_float4(0.f, 0.f, 0.f, 0.f);
    int b = rowp[n], e = rowp[n + 1];
    for (int p = b; p < e; ++p) {
        float4 v = ((const float4*)x)[csrc[p]];
        acc.x += v.x; acc.y += v.y; acc.z += v.z; acc.w += v.w;
    }
    ((float4*)out)[n] = acc;
}

// one wave per node; lanes 0..49 each own 8 contiguous features
__global__ __launch_bounds__(256) void k_aggH(const u16* __restrict__ h,
                                              const int* __restrict__ rowp,
                                              const int* __restrict__ csrc,
                                              u16* __restrict__ out) {
    int n = (blockIdx.x << 2) + (threadIdx.x >> 6);
    if (n >= NN) return;
    int l = threadIdx.x & 63;
    if (l >= 50) return;
    int b = rowp[n], e = rowp[n + 1];
    float acc[8] = {0.f, 0.f, 0.f, 0.f, 0.f, 0.f, 0.f, 0.f};
    for (int p = b; p < e; ++p) {
        const u16* r = h + (long)csrc[p] * H + l * 8;
        u16x8 v = *(const u16x8*)r;
#pragma unroll
        for (int q = 0; q < 8; ++q) acc[q] += bf2f(v[q]);
    }
    u16x8 o;
#pragma unroll
    for (int q = 0; q < 8; ++q) o[q] = f2bf(acc[q]);
    *(u16x8*)(out + (long)n * H + l * 8) = o;
}

// ---------------- first linear (K = 4), bf16 out ----------------

__global__ void k_lin0(const float* __restrict__ a4, const float* __restrict__ w,
                       const float* __restrict__ b, u16* __restrict__ out) {
    long i = (long)blockIdx.x * blockDim.x + threadIdx.x;   // over NN*100
    if (i >= (long)NN * 100) return;
    int n = (int)(i / 100), q = (int)(i - (long)n * 100);
    int j0 = q * 4;
    float4 av = ((const float4*)a4)[n];
    u16x4 o;
#pragma unroll
    for (int jj = 0; jj < 4; ++jj) {
        float4 wv = ((const float4*)w)[j0 + jj];
        float s = fmaf(av.x, wv.x, fmaf(av.y, wv.y, fmaf(av.z, wv.z, av.w * wv.w)));
        o[jj] = f2bf(s + b[j0 + jj]);
    }
    *(u16x4*)(out + (long)n * H + j0) = o;
}

// ---------------- BN stats over bf16 buffer (after lin0 only) ----------------

__global__ __launch_bounds__(256) void k_statsv(const u16* __restrict__ z,
                                                float* __restrict__ stats) {
    __shared__ float ls[800];
    int t = threadIdx.x;
    for (int i = t; i < 800; i += 256) ls[i] = 0.f;
    __syncthreads();
    if (t < 250) {
        int sub = t / 50, seg = t % 50;
        float s[8] = {0, 0, 0, 0, 0, 0, 0, 0};
        float q[8] = {0, 0, 0, 0, 0, 0, 0, 0};
        for (int r = blockIdx.x * 5 + sub; r < NN; r += gridDim.x * 5) {
            u16x8 v = *(const u16x8*)(z + (long)r * H + seg * 8);
#pragma unroll
            for (int j = 0; j < 8; ++j) {
                float f = bf2f(v[j]);
                s[j] += f; q[j] += f * f;
            }
        }
#pragma unroll
        for (int j = 0; j < 8; ++j) {
            atomicAdd(&ls[seg * 8 + j], s[j]);
            atomicAdd(&ls[400 + seg * 8 + j], q[j]);
        }
    }
    __syncthreads();
    for (int i = t; i < 800; i += 256) atomicAdd(&stats[i], ls[i]);
}

// scale/shift padded to 416 (zeros) so GEMM fragment transform can read k in [0,416)
__global__ void k_finalize(float* __restrict__ stats, const float* __restrict__ g,
                           const float* __restrict__ be, float* __restrict__ scale,
                           float* __restrict__ shift) {
    int j = blockIdx.x * blockDim.x + threadIdx.x;
    if (j >= KP) return;
    if (j >= H) { scale[j] = 0.f; shift[j] = 0.f; return; }
    float m = stats[j] / NN;
    float v = stats[H + j] / NN - m * m;
    v = fmaxf(v, 0.f);
    float rs = rsqrtf(v + EPS);
    float sc = g[j] * rs;
    scale[j] = sc;
    shift[j] = be[j] - m * sc;
    stats[j] = 0.f;          // self-clean for next use
    stats[H + j] = 0.f;
}

// ---------------- MFMA GEMM: depth-3 counted-vmcnt pipeline, fused BN+ReLU ----------------
// out[n][c] = sum_j f(A[n][j]) * Wp[c][j] + bias[c];  A: M x 400 row-major,
// Wp: 400 x 416 zero-padded. f = relu(a*scale+shift) when TRANS (applied on the
// A-fragment AFTER the LDS read, hidden under load latency), identity otherwise.
// Tile 128x80, BK=32, 13 K-tiles, 4 LDS buffers. Every wave issues exactly 4
// gload_lds per tile (seg12 staged redundantly by all waves) -> uniform vmcnt:
// steady-state vmcnt(8) keeps 2 tiles in flight + 1 being staged (depth 3).
// LDS XOR slot swizzle (R7, conflict-free). C stored via LDS bounce (coalesced).

template <bool TRANS, bool STATS, bool POOL>
__global__ __launch_bounds__(256) void gemm_mfma(const u16* __restrict__ A,
                                                 const u16* __restrict__ Wp,
                                                 const float* __restrict__ bias,
                                                 const float* __restrict__ scale,
                                                 const float* __restrict__ shift,
                                                 u16* __restrict__ out,
                                                 float* __restrict__ stats,
                                                 const int* __restrict__ batch,
                                                 float* __restrict__ pools,
                                                 int poolOff, int M) {
    constexpr int BUF = 6656;            // u16 per buffer: A 4096 + B 2560
    __shared__ u16 lds[4 * BUF];         // 53,248 B -> 3 blocks/CU

    const int t = threadIdx.x;
    // bijective XCD swizzle (nwg = 1955, not divisible by 8)
    const int nwg = gridDim.x;
    const int q8 = nwg >> 3, r8 = nwg & 7;
    const int xcd = blockIdx.x & 7, jj = blockIdx.x >> 3;
    const int wgid = (xcd < r8 ? xcd * (q8 + 1) : r8 * (q8 + 1) + (xcd - r8) * q8) + jj;
    const int bm = (wgid / 5) * 128;
    const int bn = (wgid % 5) * 80;
    const int w = t >> 6, l = t & 63;

    // staging: lane l fills LDS granule l of its seg (row l>>2, slot l&3); the
    // XOR swizzle is applied to the SOURCE address (rule #21): fetch logical
    // chunk (l&3)^((l>>3)&3) of the row.
    const int srow = l >> 2;
    const int sck  = ((l & 3) ^ ((l >> 3) & 3)) * 8;

    auto stageTile = [&](int b, int kt) {
        u16* dst = lds + b * BUF;
        const int k0 = kt * 32;
        long g0 = (long)bm + w * 16 + srow;
        long g1 = g0 + 64;
        if (g0 > M - 1) g0 = M - 1;
        if (g1 > M - 1) g1 = M - 1;
        gload_lds16(A + g0 * 400 + k0 + sck, dst + w * 512);              // A seg w
        gload_lds16(A + g1 * 400 + k0 + sck, dst + (w + 4) * 512);        // A seg w+4
        gload_lds16(Wp + (long)(bn + w * 16 + srow) * KP + k0 + sck,
                    dst + 4096 + w * 512);                                // B seg w
        gload_lds16(Wp + (long)(bn + 64 + srow) * KP + k0 + sck,
                    dst + 4096 + 4 * 512);                                // B seg 4 (x4 dup)
    };

    f32x4 acc[2][5];
#pragma unroll
    for (int i = 0; i < 2; ++i)
#pragma unroll
        for (int c = 0; c < 5; ++c)
            acc[i][c] = (f32x4){0.f, 0.f, 0.f, 0.f};

    const int r16 = l & 15;
    const int cc  = l >> 4;                          // logical k-chunk 0..3
    const int swz = r16 * 32 + (((cc ^ ((r16 >> 1) & 3))) << 3);

    auto computeTile = [&](int b, int s) {
        const u16* base = lds + b * BUF;
        const u16* ab = base + w * 1024 + swz;       // segs 2w, 2w+1
        const u16* bb = base + 4096 + swz;
        bf16x8 fa0 = *(const bf16x8*)ab;
        bf16x8 fa1 = *(const bf16x8*)(ab + 512);
        if (TRANS) {
            const int k = s * 32 + cc * 8;           // <= 408, arrays padded to 416
            float4 sc0 = *(const float4*)(scale + k);
            float4 sc1 = *(const float4*)(scale + k + 4);
            float4 sh0 = *(const float4*)(shift + k);
            float4 sh1 = *(const float4*)(shift + k + 4);
            u16x8 a0 = (u16x8)fa0, a1 = (u16x8)fa1;
            u16x8 o0, o1;
            o0[0] = f2bf(fmaxf(fmaf(bf2f(a0[0]), sc0.x, sh0.x), 0.f));
            o0[1] = f2bf(fmaxf(fmaf(bf2f(a0[1]), sc0.y, sh0.y), 0.f));
            o0[2] = f2bf(fmaxf(fmaf(bf2f(a0[2]), sc0.z, sh0.z), 0.f));
            o0[3] = f2bf(fmaxf(fmaf(bf2f(a0[3]), sc0.w, sh0.w), 0.f));
            o0[4] = f2bf(fmaxf(fmaf(bf2f(a0[4]), sc1.x, sh1.x), 0.f));
            o0[5] = f2bf(fmaxf(fmaf(bf2f(a0[5]), sc1.y, sh1.y), 0.f));
            o0[6] = f2bf(fmaxf(fmaf(bf2f(a0[6]), sc1.z, sh1.z), 0.f));
            o0[7] = f2bf(fmaxf(fmaf(bf2f(a0[7]), sc1.w, sh1.w), 0.f));
            o1[0] = f2bf(fmaxf(fmaf(bf2f(a1[0]), sc0.x, sh0.x), 0.f));
            o1[1] = f2bf(fmaxf(fmaf(bf2f(a1[1]), sc0.y, sh0.y), 0.f));
            o1[2] = f2bf(fmaxf(fmaf(bf2f(a1[2]), sc0.z, sh0.z), 0.f));
            o1[3] = f2bf(fmaxf(fmaf(bf2f(a1[3]), sc0.w, sh0.w), 0.f));
            o1[4] = f2bf(fmaxf(fmaf(bf2f(a1[4]), sc1.x, sh1.x), 0.f));
            o1[5] = f2bf(fmaxf(fmaf(bf2f(a1[5]), sc1.y, sh1.y), 0.f));
            o1[6] = f2bf(fmaxf(fmaf(bf2f(a1[6]), sc1.z, sh1.z), 0.f));
            o1[7] = f2bf(fmaxf(fmaf(bf2f(a1[7]), sc1.w, sh1.w), 0.f));
            fa0 = (bf16x8)o0;
            fa1 = (bf16x8)o1;
        }
        __builtin_amdgcn_s_setprio(1);
#pragma unroll
        for (int c = 0; c < 5; ++c) {
            bf16x8 fb = *(const bf16x8*)(bb + c * 512);
            acc[0][c] = __builtin_amdgcn_mfma_f32_16x16x32_bf16(fa0, fb, acc[0][c], 0, 0, 0);
            acc[1][c] = __builtin_amdgcn_mfma_f32_16x16x32_bf16(fa1, fb, acc[1][c], 0, 0, 0);
        }
        __builtin_amdgcn_s_setprio(0);
    };

    // prologue: tiles 0,1,2 in flight (12 loads/wave)
    stageTile(0, 0);
    stageTile(1, 1);
    stageTile(2, 2);

#pragma unroll 1
    for (int s = 0; s < 11; ++s) {
        asm volatile("s_waitcnt vmcnt(8)" ::: "memory");   // own tile-s loads done
        __builtin_amdgcn_s_barrier();                      // all waves' tile-s done
        if (s + 3 < 13) stageTile((s + 3) & 3, s + 3);
        computeTile(s & 3, s);
    }
    asm volatile("s_waitcnt vmcnt(4)" ::: "memory");
    __builtin_amdgcn_s_barrier();
    computeTile(11 & 3, 11);
    asm volatile("s_waitcnt vmcnt(0)" ::: "memory");
    __builtin_amdgcn_s_barrier();
    computeTile(12 & 3, 12);

    // ---- epilogue: LDS-bounced coalesced stores + fused stats/pool ----
    u16*   tile = lds;                       // 128x80 u16 = 10240
    float* sst  = (float*)(lds + 20480);     // 160 floats
    float* pacc = sst + 160;                 // 480 floats
    __syncthreads();                         // tile-12 reads done everywhere
    if (STATS) for (int i = t; i < 160; i += 256) sst[i] = 0.f;
    if (POOL)  for (int i = t; i < 480; i += 256) pacc[i] = 0.f;
    __syncthreads();

    int sg0 = 0, span = 0;
    int grow[2][4];
    if (POOL) {
        sg0 = batch[min(bm, M - 1)];
        span = batch[min(bm + 127, M - 1)] - sg0 + 1;
#pragma unroll
        for (int i = 0; i < 2; ++i) {
            int rbase = bm + w * 32 + i * 16 + (l >> 4) * 4;
#pragma unroll
            for (int r = 0; r < 4; ++r)
                grow[i][r] = (rbase + r < M) ? batch[rbase + r] : -1;
        }
    }

    // C/D layout: col=lane&15, row=(lane>>4)*4+reg
    float ssum[5], sqq[5];
#pragma unroll
    for (int c = 0; c < 5; ++c) { ssum[c] = 0.f; sqq[c] = 0.f; }
#pragma unroll
    for (int i = 0; i < 2; ++i) {
        const int lrow0 = w * 32 + i * 16 + (l >> 4) * 4;   // local row base
#pragma unroll
        for (int c = 0; c < 5; ++c) {
            const int lcol = c * 16 + (l & 15);
            const float bv = bias[bn + lcol];
#pragma unroll
            for (int r = 0; r < 4; ++r) {
                const int lrow = lrow0 + r;
                float z = acc[i][c][r] + bv;
                tile[lrow * 80 + lcol] = f2bf(z);
                if (bm + lrow < M) {
                    if (STATS) { ssum[c] += z; sqq[c] += z * z; }
                    if (POOL) {
                        int g = grow[i][r];
                        if (span <= 6)
                            atomicAdd(&pacc[(g - sg0) * 80 + lcol], z);
                        else
                            atomicAdd(&pools[(long)g * 1200 + poolOff + bn + lcol], z);
                    }
                }
            }
        }
    }
    __syncthreads();
    // coalesced copy-out: 1280 16B chunks, 5 per thread
#pragma unroll
    for (int j = 0; j < 5; ++j) {
        int chunk = t + j * 256;
        int row = chunk / 10, c8 = chunk % 10;
        if (bm + row < M) {
            u16x8 v = *(const u16x8*)(tile + row * 80 + c8 * 8);
            *(u16x8*)(out + (long)(bm + row) * H + bn + c8 * 8) = v;
        }
    }
    if (STATS) {
#pragma unroll
        for (int c = 0; c < 5; ++c) {
            ssum[c] += __shfl_xor(ssum[c], 16); ssum[c] += __shfl_xor(ssum[c], 32);
            sqq[c]  += __shfl_xor(sqq[c], 16);  sqq[c]  += __shfl_xor(sqq[c], 32);
        }
        if (l < 16) {
#pragma unroll
            for (int c = 0; c < 5; ++c) {
                atomicAdd(&sst[c * 16 + l], ssum[c]);
                atomicAdd(&sst[80 + c * 16 + l], sqq[c]);
            }
        }
        __syncthreads();
        if (t < 80)       atomicAdd(&stats[bn + t], sst[t]);
        else if (t < 160) atomicAdd(&stats[H + bn + (t - 80)], sst[t]);
    }
    if (POOL) {
        __syncthreads();
        if (span <= 6) {
            int nsp = span * 80;
            for (int i = t; i < nsp; i += 256) {
                atomicAdd(&pools[(long)(sg0 + i / 80) * 1200 + poolOff + bn + (i % 80)],
                          pacc[i]);
            }
        }
    }
}

// ---------------- readout ----------------

__global__ __launch_bounds__(256) void k_lin1(const float* __restrict__ pools,
                                              const float* __restrict__ w1,
                                              const float* __restrict__ b1,
                                              float* __restrict__ zz) {
    __shared__ __align__(16) float xg[1200];
    int band = blockIdx.x, g = blockIdx.y, t = threadIdx.x;
    for (int i = t; i < 1200; i += 256) xg[i] = pools[(long)g * 1200 + i];
    __syncthreads();
    if (t < 240) {
        int j = band * 120 + (t >> 1);
        int kh = t & 1;
        const float4* wr = (const float4*)(w1 + (long)j * 1200 + kh * 600);
        const float4* xr = (const float4*)(xg + kh * 600);
        float s = 0.f;
        for (int q = 0; q < 150; ++q) {
            float4 a = xr[q], b = wr[q];
            s = fmaf(a.x, b.x, s); s = fmaf(a.y, b.y, s);
            s = fmaf(a.z, b.z, s); s = fmaf(a.w, b.w, s);
        }
        s += __shfl_xor(s, 1);
        if (!kh) zz[(long)g * 600 + j] = fmaxf(s + b1[j], 0.f);
    }
}

__global__ __launch_bounds__(64) void k_lin2(const float* __restrict__ zz,
                                             const float* __restrict__ w2,
                                             const float* __restrict__ b2,
                                             float* __restrict__ out) {
    int g = blockIdx.x;
    int l = threadIdx.x;
    float p[NC];
#pragma unroll
    for (int c = 0; c < NC; ++c) p[c] = 0.f;
    for (int k = l; k < 600; k += 64) {
        float zv = zz[(long)g * 600 + k];
#pragma unroll
        for (int c = 0; c < NC; ++c) p[c] = fmaf(zv, w2[c * 600 + k], p[c]);
    }
#pragma unroll
    for (int c = 0; c < NC; ++c)
#pragma unroll
        for (int o = 32; o; o >>= 1) p[c] += __shfl_xor(p[c], o);
    if (l == 0) {
        float lg[NC];
        float mx = -1e30f;
#pragma unroll
        for (int c = 0; c < NC; ++c) { lg[c] = p[c] + b2[c]; mx = fmaxf(mx, lg[c]); }
        float se = 0.f;
#pragma unroll
        for (int c = 0; c < NC; ++c) se += expf(lg[c] - mx);
        float lse = logf(se);
#pragma unroll
        for (int c = 0; c < NC; ++c) out[(long)g * NC + c] = lg[c] - mx - lse;
    }
}

// ---------------- launch ----------------

extern "C" void kernel_launch(void* const* d_in, const int* in_sizes, int n_in,
                              void* d_out, int out_size, void* d_ws, size_t ws_size,
                              hipStream_t stream) {
    const float* x      = (const float*)d_in[0];
    const int*   ei     = (const int*)d_in[1];
    const int*   batch  = (const int*)d_in[2];
    const float* c0_w1  = (const float*)d_in[4];
    const float* c0_b1  = (const float*)d_in[5];
    const float* c0_g1  = (const float*)d_in[6];
    const float* c0_be1 = (const float*)d_in[7];
    const float* c0_w2  = (const float*)d_in[8];
    const float* c0_b2  = (const float*)d_in[9];
    const float* c0_g2  = (const float*)d_in[10];
    const float* c0_be2 = (const float*)d_in[11];
    const float* c0_w3  = (const float*)d_in[12];
    const float* c0_b3  = (const float*)d_in[13];
    const float* cw1    = (const float*)d_in[14];
    const float* cb1    = (const float*)d_in[15];
    const float* cg1    = (const float*)d_in[16];
    const float* cbe1   = (const float*)d_in[17];
    const float* cw2    = (const float*)d_in[18];
    const float* cb2    = (const float*)d_in[19];
    const float* cg2    = (const float*)d_in[20];
    const float* cbe2   = (const float*)d_in[21];
    const float* cw3    = (const float*)d_in[22];
    const float* cb3    = (const float*)d_in[23];
    const float* lin1_w = (const float*)d_in[24];
    const float* lin1_b = (const float*)d_in[25];
    const float* lin2_w = (const float*)d_in[26];
    const float* lin2_b = (const float*)d_in[27];

    const int* src = ei;
    const int* dst = ei + NE;

    char* ws = (char*)d_ws;
    size_t off = 0;
    auto alloc = [&](size_t bytes) {
        void* p = ws + off;
        off += (bytes + 255) & ~(size_t)255;
        return p;
    };
    u16*   bufh  = (u16*)alloc((size_t)NN * H * 2 + 128);   // +: K-tail overread pad
    u16*   bufa  = (u16*)alloc((size_t)NN * H * 2 + 128);
    float* agg0  = (float*)alloc((size_t)NN * 4 * 4);
    float* stats = (float*)alloc(2 * H * 4);
    float* scale = (float*)alloc(KP * 4);
    float* shift = (float*)alloc(KP * 4);
    float* pools = (float*)alloc((size_t)NG * 3 * H * 4);
    float* zz    = (float*)alloc((size_t)NG * 600 * 4);
    // padded bf16 weights [8][400][416]: w2_0 | w3_0 | w1[2] | w2[2] | w3[2]
    u16*   wpad  = (u16*)alloc((size_t)8 * 400 * KP * 2);
    int*   deg   = (int*)alloc((size_t)NN * 4);
    int*   rowp  = (int*)alloc((size_t)(NN + 1) * 4);
    int*   cur   = (int*)alloc((size_t)NN * 4);
    int*   csrc  = (int*)alloc((size_t)NE * 4);
    int*   part  = (int*)alloc((size_t)NN * 4);
    int*   btot  = (int*)alloc((size_t)NB1 * 4);

    auto wp = [&](int mat) { return wpad + (size_t)mat * 400 * KP; };

    hipMemsetAsync(deg, 0, (size_t)NN * 4, stream);
    hipMemsetAsync(stats, 0, 2 * H * 4, stream);
    hipMemsetAsync(pools, 0, (size_t)NG * 3 * H * 4, stream);

    k_cvtw_all<<<(8 * 400 * 52 + 255) / 256, 256, 0, stream>>>(c0_w2, c0_w3, cw1, cw2, cw3,
                                                               wpad);

    // CSR build
    k_count<<<(NE + 255) / 256, 256, 0, stream>>>(dst, deg);
    k_scan1<<<NB1, 256, 0, stream>>>(deg, part, btot);
    k_scan2<<<1, 256, 0, stream>>>(btot);
    k_scan3<<<NB1, 256, 0, stream>>>(part, btot, deg, rowp, cur);
    k_scatter<<<(NE + 255) / 256, 256, 0, stream>>>(src, dst, cur, csrc);

    const int ngemm = ((NN + 127) / 128) * 5;   // 1955 blocks

    // layer 0
    k_agg0<<<(NN + 255) / 256, 256, 0, stream>>>(x, rowp, csrc, agg0);
    k_lin0<<<(int)(((long)NN * 100 + 255) / 256), 256, 0, stream>>>(agg0, c0_w1, c0_b1, bufh);
    k_statsv<<<96, 256, 0, stream>>>(bufh, stats);
    k_finalize<<<2, 256, 0, stream>>>(stats, c0_g1, c0_be1, scale, shift);
    gemm_mfma<true, true, false><<<ngemm, 256, 0, stream>>>(bufh, wp(0), c0_b2, scale, shift,
                                                            bufa, stats, nullptr, nullptr,
                                                            0, NN);
    k_finalize<<<2, 256, 0, stream>>>(stats, c0_g2, c0_be2, scale, shift);
    gemm_mfma<true, false, true><<<ngemm, 256, 0, stream>>>(bufa, wp(1), c0_b3, scale, shift,
                                                            bufh, nullptr, batch, pools,
                                                            0, NN);

    // layers 1..2
    for (int l = 0; l < 2; ++l) {
        k_aggH<<<(NN + 3) / 4, 256, 0, stream>>>(bufh, rowp, csrc, bufa);
        gemm_mfma<false, true, false><<<ngemm, 256, 0, stream>>>(bufa, wp(2 + l), cb1 + l * H,
                                                                 nullptr, nullptr, bufh,
                                                                 stats, nullptr, nullptr,
                                                                 0, NN);
        k_finalize<<<2, 256, 0, stream>>>(stats, cg1 + l * H, cbe1 + l * H, scale, shift);
        gemm_mfma<true, true, false><<<ngemm, 256, 0, stream>>>(bufh, wp(4 + l), cb2 + l * H,
                                                                scale, shift, bufa, stats,
                                                                nullptr, nullptr, 0, NN);
        k_finalize<<<2, 256, 0, stream>>>(stats, cg2 + l * H, cbe2 + l * H, scale, shift);
        gemm_mfma<true, false, true><<<ngemm, 256, 0, stream>>>(bufa, wp(6 + l), cb3 + l * H,
                                                                scale, shift, bufh, nullptr,
                                                                batch, pools, (l + 1) * H, NN);
    }

    // readout
    dim3 gl1(5, NG);
    k_lin1<<<gl1, 256, 0, stream>>>(pools, lin1_w, lin1_b, zz);
    k_lin2<<<NG, 64, 0, stream>>>(zz, lin2_w, lin2_b, (float*)d_out);
}